// Round 9
// baseline (126.467 us; speedup 1.0000x reference)
//
#include <hip/hip_runtime.h>

#define DIM    1024
#define BATCH  8
#define SEQ    2048
#define NBLK   512
#define NTHR   256
#define CHUNKS 64
#define ROWS   (SEQ / CHUNKS)   // 32 rows per P1 block
#define LN_EPS 1e-5f

typedef float v4 __attribute__((ext_vector_type(4)));
typedef unsigned long long u64;

__device__ __forceinline__ float dot4(v4 a, v4 b) {
  return a.x * b.x + a.y * b.y + a.z * b.z + a.w * b.w;
}

__device__ __forceinline__ float wred(float a) {
#pragma unroll
  for (int m = 32; m; m >>= 1) a += __shfl_xor(a, m, 64);
  return a;
}

// ---------------------------------------------------------------------------
// Fence-free grid barrier. Valid ONLY because all cross-block data in this
// kernel moves through device-scope atomics (coherent point, cache-bypassing):
// no dirty L2 lines need writeback, no stale lines can be read (x/weights are
// read-only; out is write-only). s_waitcnt vmcnt(0) = all our atomics acked.
// ---------------------------------------------------------------------------
__device__ __forceinline__ void bar_sync(unsigned* cnt, unsigned* flag) {
  __syncthreads();
  asm volatile("s_waitcnt vmcnt(0)" ::: "memory");
  if (threadIdx.x == 0) {
    unsigned prev = __hip_atomic_fetch_add(cnt, 1u, __ATOMIC_RELAXED,
                                           __HIP_MEMORY_SCOPE_AGENT);
    if (prev == NBLK - 1u) {
      __hip_atomic_store(flag, 1u, __ATOMIC_RELAXED,
                         __HIP_MEMORY_SCOPE_AGENT);
    } else {
      while (__hip_atomic_load(flag, __ATOMIC_RELAXED,
                               __HIP_MEMORY_SCOPE_AGENT) == 0u)
        __builtin_amdgcn_s_sleep(8);
    }
  }
  asm volatile("" ::: "memory");  // compiler-only: no atomic hoisting
  __syncthreads();
}

// ---------------------------------------------------------------------------
// Fused kernel, 4 phases / 3 fence-free barriers. 512 blocks x 256 thr.
//  P1: colsum of x over s -> atomicAdd into xsum   (x -> L3 as side effect)
//  P2: vsum = xsum @ Wv^T      (xsum via atomic loads -> LDS)
//  P3: z    = vsum @ Wfc^T + b (vsum via atomic loads -> LDS)
//  P4: out  = LN(x + z)*gamma + beta   (x re-read: L3 hit; z -> LDS)
// ---------------------------------------------------------------------------
__global__ __launch_bounds__(NTHR, 4) void k_fused(
    const float* __restrict__ x, const float* __restrict__ w_v,
    const float* __restrict__ w_fc, const float* __restrict__ b_fc,
    const float* __restrict__ gamma, const float* __restrict__ beta,
    float* __restrict__ out, unsigned* __restrict__ bar,
    float* __restrict__ xsum, float* __restrict__ vsum,
    float* __restrict__ z) {
  __shared__ float smem[DIM];
  const int blk = blockIdx.x, t = threadIdx.x;
  const int wv = t >> 6, lane = t & 63;
  const int b = blk >> 6;  // 64 blocks per batch, all phases

  // -------- P1: partial colsum + atomicAdd into xsum --------
  {
    const int c = blk & (CHUNKS - 1);
    const v4* base = (const v4*)x + ((size_t)(b * SEQ + c * ROWS) << 8) + t;
    v4 a0 = {0.f, 0.f, 0.f, 0.f}, a1 = {0.f, 0.f, 0.f, 0.f};
#pragma unroll
    for (int s = 0; s < ROWS; s += 2) {
      a0 += base[(size_t)s << 8];
      a1 += base[(size_t)(s + 1) << 8];
    }
    v4 a = a0 + a1;
    float* xp = xsum + (b << 10) + (t << 2);
    atomicAdd(xp + 0, a.x);
    atomicAdd(xp + 1, a.y);
    atomicAdd(xp + 2, a.z);
    atomicAdd(xp + 3, a.w);
  }
  bar_sync(bar + 0, bar + 1);

  // -------- P2: vsum = xsum @ Wv^T (block: 16 outputs of batch b) --------
  {
    const u64* src = (const u64*)(xsum + (b << 10));
#pragma unroll
    for (int k = 0; k < 2; ++k)
      ((u64*)smem)[t + 256 * k] = __hip_atomic_load(
          src + t + 256 * k, __ATOMIC_RELAXED, __HIP_MEMORY_SCOPE_AGENT);
    __syncthreads();

    v4 xf[4];
#pragma unroll
    for (int j = 0; j < 4; ++j) xf[j] = ((const v4*)smem)[lane + 64 * j];

    const int obase = blk * 16 + wv * 4;
    const int dbase = obase & (DIM - 1);
    v4 w0[4], w1[4], w2[4], w3[4];
#pragma unroll
    for (int j = 0; j < 4; ++j) {
      w0[j] = ((const v4*)w_v + ((size_t)(dbase + 0) << 8))[lane + 64 * j];
      w1[j] = ((const v4*)w_v + ((size_t)(dbase + 1) << 8))[lane + 64 * j];
      w2[j] = ((const v4*)w_v + ((size_t)(dbase + 2) << 8))[lane + 64 * j];
      w3[j] = ((const v4*)w_v + ((size_t)(dbase + 3) << 8))[lane + 64 * j];
    }
    float a0 = 0.f, a1 = 0.f, a2 = 0.f, a3 = 0.f;
#pragma unroll
    for (int j = 0; j < 4; ++j) {
      a0 += dot4(w0[j], xf[j]);
      a1 += dot4(w1[j], xf[j]);
      a2 += dot4(w2[j], xf[j]);
      a3 += dot4(w3[j], xf[j]);
    }
    a0 = wred(a0); a1 = wred(a1); a2 = wred(a2); a3 = wred(a3);
    if (lane == 0) {
      __hip_atomic_store(vsum + obase + 0, a0, __ATOMIC_RELAXED,
                         __HIP_MEMORY_SCOPE_AGENT);
      __hip_atomic_store(vsum + obase + 1, a1, __ATOMIC_RELAXED,
                         __HIP_MEMORY_SCOPE_AGENT);
      __hip_atomic_store(vsum + obase + 2, a2, __ATOMIC_RELAXED,
                         __HIP_MEMORY_SCOPE_AGENT);
      __hip_atomic_store(vsum + obase + 3, a3, __ATOMIC_RELAXED,
                         __HIP_MEMORY_SCOPE_AGENT);
    }
  }
  bar_sync(bar + 2, bar + 3);

  // -------- P3: z = vsum @ Wfc^T + b_fc --------
  {
    const u64* src = (const u64*)(vsum + (b << 10));
#pragma unroll
    for (int k = 0; k < 2; ++k)
      ((u64*)smem)[t + 256 * k] = __hip_atomic_load(
          src + t + 256 * k, __ATOMIC_RELAXED, __HIP_MEMORY_SCOPE_AGENT);
    __syncthreads();

    v4 vf[4];
#pragma unroll
    for (int j = 0; j < 4; ++j) vf[j] = ((const v4*)smem)[lane + 64 * j];

    const int obase = blk * 16 + wv * 4;
    const int dbase = obase & (DIM - 1);
    v4 w0[4], w1[4], w2[4], w3[4];
#pragma unroll
    for (int j = 0; j < 4; ++j) {
      w0[j] = ((const v4*)w_fc + ((size_t)(dbase + 0) << 8))[lane + 64 * j];
      w1[j] = ((const v4*)w_fc + ((size_t)(dbase + 1) << 8))[lane + 64 * j];
      w2[j] = ((const v4*)w_fc + ((size_t)(dbase + 2) << 8))[lane + 64 * j];
      w3[j] = ((const v4*)w_fc + ((size_t)(dbase + 3) << 8))[lane + 64 * j];
    }
    float a0 = 0.f, a1 = 0.f, a2 = 0.f, a3 = 0.f;
#pragma unroll
    for (int j = 0; j < 4; ++j) {
      a0 += dot4(w0[j], vf[j]);
      a1 += dot4(w1[j], vf[j]);
      a2 += dot4(w2[j], vf[j]);
      a3 += dot4(w3[j], vf[j]);
    }
    a0 = wred(a0); a1 = wred(a1); a2 = wred(a2); a3 = wred(a3);
    if (lane == 0) {
      __hip_atomic_store(z + obase + 0, a0 + b_fc[dbase + 0],
                         __ATOMIC_RELAXED, __HIP_MEMORY_SCOPE_AGENT);
      __hip_atomic_store(z + obase + 1, a1 + b_fc[dbase + 1],
                         __ATOMIC_RELAXED, __HIP_MEMORY_SCOPE_AGENT);
      __hip_atomic_store(z + obase + 2, a2 + b_fc[dbase + 2],
                         __ATOMIC_RELAXED, __HIP_MEMORY_SCOPE_AGENT);
      __hip_atomic_store(z + obase + 3, a3 + b_fc[dbase + 3],
                         __ATOMIC_RELAXED, __HIP_MEMORY_SCOPE_AGENT);
    }
  }
  bar_sync(bar + 4, bar + 5);

  // -------- P4: out = LN(x + z)*gamma + beta (32 rows/block) --------
  {
    const u64* src = (const u64*)(z + (b << 10));
#pragma unroll
    for (int k = 0; k < 2; ++k)
      ((u64*)smem)[t + 256 * k] = __hip_atomic_load(
          src + t + 256 * k, __ATOMIC_RELAXED, __HIP_MEMORY_SCOPE_AGENT);
    __syncthreads();

    v4 zf[4], gf[4], bf[4];
#pragma unroll
    for (int j = 0; j < 4; ++j) {
      zf[j] = ((const v4*)smem)[lane + 64 * j];
      gf[j] = ((const v4*)gamma)[lane + 64 * j];
      bf[j] = ((const v4*)beta)[lane + 64 * j];
    }

#pragma unroll 1
    for (int r = 0; r < 8; ++r) {
      const int row = blk * 32 + wv * 8 + r;
      const v4* xr = (const v4*)x + ((size_t)row << 8);
      v4 h[4];
      float sum = 0.f, ss = 0.f;
#pragma unroll
      for (int j = 0; j < 4; ++j) {
        v4 hv = xr[lane + 64 * j] + zf[j];
        h[j] = hv;
        sum += hv.x + hv.y + hv.z + hv.w;
        ss  += hv.x * hv.x + hv.y * hv.y + hv.z * hv.z + hv.w * hv.w;
      }
#pragma unroll
      for (int m = 32; m; m >>= 1) {
        sum += __shfl_xor(sum, m, 64);
        ss  += __shfl_xor(ss,  m, 64);
      }
      const float inv = 1.0f / (float)DIM;
      const float mu = sum * inv;
      const float rs = rsqrtf(ss * inv - mu * mu + LN_EPS);

      v4* outr = (v4*)out + ((size_t)row << 8);
#pragma unroll
      for (int j = 0; j < 4; ++j)
        outr[lane + 64 * j] = (h[j] - mu) * rs * gf[j] + bf[j];
    }
  }
}

// ------------------- fallback (multi-kernel, proven R8 path) ---------------
__global__ __launch_bounds__(256, 4) void k_partial_colsum(
    const float* __restrict__ x, float* __restrict__ partial) {
  const int blk = blockIdx.x;
  const int b = blk >> 6, c = blk & (CHUNKS - 1), t = threadIdx.x;
  const v4* base = (const v4*)x + ((size_t)(b * SEQ + c * ROWS) << 8) + t;
  v4 a0 = {0.f, 0.f, 0.f, 0.f}, a1 = {0.f, 0.f, 0.f, 0.f};
#pragma unroll
  for (int s = 0; s < ROWS; s += 2) {
    a0 += base[(size_t)s << 8];
    a1 += base[(size_t)(s + 1) << 8];
  }
  ((v4*)partial)[((size_t)(c * BATCH + b) << 8) + t] = a0 + a1;
}

__global__ __launch_bounds__(256) void k_finish_colsum(
    const float* __restrict__ partial, float* __restrict__ xsum) {
  const int t = threadIdx.x;
  const int i4 = blockIdx.x * 32 + (t >> 3);
  const int grp = t & 7;
  const int b = i4 >> 8, e4 = i4 & 255;
  const v4* p = (const v4*)partial + ((size_t)b << 8) + e4;
  v4 acc = {0.f, 0.f, 0.f, 0.f};
#pragma unroll
  for (int k = 0; k < 8; ++k)
    acc += p[(size_t)(grp + 8 * k) * (BATCH * 256)];
#pragma unroll
  for (int m = 4; m; m >>= 1) {
    acc.x += __shfl_xor(acc.x, m, 64);
    acc.y += __shfl_xor(acc.y, m, 64);
    acc.z += __shfl_xor(acc.z, m, 64);
    acc.w += __shfl_xor(acc.w, m, 64);
  }
  if (grp == 0) ((v4*)xsum)[i4] = acc;
}

__global__ __launch_bounds__(256) void k_gemv(
    const float* __restrict__ vin, const float* __restrict__ W,
    const float* __restrict__ bias, float* __restrict__ vout) {
  const int wv = threadIdx.x >> 6, lane = threadIdx.x & 63;
  const int o = blockIdx.x * 4 + wv;
  const int b = o >> 10, d = o & (DIM - 1);
  const v4* in4 = (const v4*)vin + ((size_t)b << 8);
  const v4* w4  = (const v4*)W + ((size_t)d << 8);
  float acc = 0.f;
#pragma unroll
  for (int j = 0; j < 4; ++j)
    acc += dot4(w4[lane + 64 * j], in4[lane + 64 * j]);
  acc = wred(acc);
  if (lane == 0) {
    float r = acc;
    if (bias) r += bias[d];
    vout[o] = r;
  }
}

__global__ __launch_bounds__(256, 4) void k_residual_ln(
    const float* __restrict__ x, const float* __restrict__ z,
    const float* __restrict__ gamma, const float* __restrict__ beta,
    float* __restrict__ out) {
  __shared__ float zl[DIM];
  const int blk = blockIdx.x, t = threadIdx.x;
  const int wv = t >> 6, lane = t & 63;
  const int b = blk >> 7;
  ((v4*)zl)[t] = ((const v4*)z)[((size_t)b << 8) + t];
  __syncthreads();
  v4 zf[4], gf[4], bf[4];
#pragma unroll
  for (int j = 0; j < 4; ++j) {
    zf[j] = ((const v4*)zl)[lane + 64 * j];
    gf[j] = ((const v4*)gamma)[lane + 64 * j];
    bf[j] = ((const v4*)beta)[lane + 64 * j];
  }
#pragma unroll 1
  for (int r = 0; r < 4; ++r) {
    const int row = (blk << 4) + (wv << 2) + r;
    const v4* xr = (const v4*)x + ((size_t)row << 8);
    v4 h[4];
    float sum = 0.f, ss = 0.f;
#pragma unroll
    for (int j = 0; j < 4; ++j) {
      v4 hv = xr[lane + 64 * j] + zf[j];
      h[j] = hv;
      sum += hv.x + hv.y + hv.z + hv.w;
      ss  += hv.x * hv.x + hv.y * hv.y + hv.z * hv.z + hv.w * hv.w;
    }
#pragma unroll
    for (int m = 32; m; m >>= 1) {
      sum += __shfl_xor(sum, m, 64);
      ss  += __shfl_xor(ss,  m, 64);
    }
    const float inv = 1.0f / (float)DIM;
    const float mu = sum * inv;
    const float rs = rsqrtf(ss * inv - mu * mu + LN_EPS);
    v4* outr = (v4*)out + ((size_t)row << 8);
#pragma unroll
    for (int j = 0; j < 4; ++j)
      outr[lane + 64 * j] = (h[j] - mu) * rs * gf[j] + bf[j];
  }
}

extern "C" void kernel_launch(void* const* d_in, const int* in_sizes, int n_in,
                              void* d_out, int out_size, void* d_ws, size_t ws_size,
                              hipStream_t stream) {
  const float* x     = (const float*)d_in[0];   // [B, S, D]
  const float* w_qkv = (const float*)d_in[1];   // [3D, D]
  const float* w_fc  = (const float*)d_in[2];   // [D, D]
  const float* b_fc  = (const float*)d_in[3];   // [D]
  const float* gamma = (const float*)d_in[4];   // [D]
  const float* beta  = (const float*)d_in[5];   // [D]
  float* out = (float*)d_out;

  // ws layout: [bar 256B][xsum 32KB][vsum 32KB][z 32KB][partial 2MB (fallback)]
  unsigned* bar  = (unsigned*)d_ws;
  float* xsum    = (float*)((char*)d_ws + 256);
  float* vsum    = xsum + BATCH * DIM;
  float* z       = vsum + BATCH * DIM;
  float* partial = z + BATCH * DIM;

  const float* w_v = w_qkv + (size_t)2 * DIM * DIM;  // rows [2D,3D) of w_qkv

  // Zero barrier words + xsum accumulator (one small graph node).
  (void)hipMemsetAsync(d_ws, 0, 256 + BATCH * DIM * sizeof(float), stream);

  void* args[] = {(void*)&x,    (void*)&w_v,   (void*)&w_fc, (void*)&b_fc,
                  (void*)&gamma, (void*)&beta, (void*)&out,  (void*)&bar,
                  (void*)&xsum, (void*)&vsum,  (void*)&z};
  hipError_t err = hipLaunchCooperativeKernel((void*)k_fused, dim3(NBLK),
                                              dim3(NTHR), args, 0, stream);
  if (err != hipSuccess) {
    hipLaunchKernelGGL(k_partial_colsum, dim3(BATCH * CHUNKS), dim3(256), 0,
                       stream, x, partial);
    hipLaunchKernelGGL(k_finish_colsum, dim3(64), dim3(256), 0, stream,
                       partial, xsum);
    hipLaunchKernelGGL(k_gemv, dim3(BATCH * DIM / 4), dim3(256), 0, stream,
                       xsum, w_v, (const float*)nullptr, vsum);
    hipLaunchKernelGGL(k_gemv, dim3(BATCH * DIM / 4), dim3(256), 0, stream,
                       vsum, w_fc, b_fc, z);
    hipLaunchKernelGGL(k_residual_ln, dim3(BATCH * SEQ / 16), dim3(256), 0,
                       stream, x, z, gamma, beta, out);
  }
}